// Round 6
// baseline (17491.531 us; speedup 1.0000x reference)
//
#include <hip/hip_runtime.h>

#define S_  1024
#define B_  64
#define P_  32

typedef _Float16 f16;
typedef unsigned int u32;
typedef _Float16 half2_t __attribute__((ext_vector_type(2)));
typedef _Float16 half8_t __attribute__((ext_vector_type(8)));

__device__ __forceinline__ float dot8(half8_t w, half8_t h, float acc) {
#if __has_builtin(__builtin_amdgcn_fdot2)
    acc = __builtin_amdgcn_fdot2((half2_t){w[0], w[1]}, (half2_t){h[0], h[1]}, acc, false);
    acc = __builtin_amdgcn_fdot2((half2_t){w[2], w[3]}, (half2_t){h[2], h[3]}, acc, false);
    acc = __builtin_amdgcn_fdot2((half2_t){w[4], w[5]}, (half2_t){h[4], h[5]}, acc, false);
    acc = __builtin_amdgcn_fdot2((half2_t){w[6], w[7]}, (half2_t){h[6], h[7]}, acc, false);
#else
    #pragma unroll
    for (int j = 0; j < 8; ++j) acc += (float)w[j] * (float)h[j];
#endif
    return acc;
}

__device__ __forceinline__ float fast_sig(float x)  { return 1.f / (1.f + __expf(-x)); }
__device__ __forceinline__ float fast_tanh(float x) { return 1.f - 2.f / (1.f + __expf(2.f * x)); }

// ---- prep: swizzle weights for k_lstm's access pattern ----
__global__ void k_prep_w(const float* __restrict__ wih_f, const float* __restrict__ whh_f,
                         const float* __restrict__ bih_f, const float* __restrict__ bhh_f,
                         const float* __restrict__ wih_b, const float* __restrict__ whh_b,
                         const float* __restrict__ bih_b, const float* __restrict__ bhh_b,
                         f16* __restrict__ Whh_sw, f16* __restrict__ Wx_sw,
                         float* __restrict__ bias2) {
    int rowg = blockIdx.x;          // 0..2047
    int dir = rowg >> 10;
    int r = rowg & 1023;
    int col = threadIdx.x;          // 0..383
    int g = r >> 8, half = (r >> 7) & 1, u = r & 127;
    int rloc = g * 128 + u;
    const float* wih = dir ? wih_b : wih_f;
    const float* whh = dir ? whh_b : whh_f;
    if (col < 128) {
        int q = col >> 6, c = (col >> 3) & 7, j = col & 7;
        Wx_sw[(((((size_t)dir * 2 + half) * 2 + q) * 8 + c) * 512 + rloc) * 8 + j] =
            (f16)wih[r * 128 + col];
    } else {
        int v = col - 128;              // 0..255 h-column
        int cc = v >> 3, j = v & 7;
        int q = cc & 1, cp = cc >> 1;
        Whh_sw[(((((size_t)dir * 2 + half) * 2 + q) * 16 + cp) * 512 + rloc) * 8 + j] =
            (f16)whh[r * 256 + v];
    }
    if (col == 0) {
        const float* bi = dir ? bih_b : bih_f;
        const float* bh = dir ? bhh_b : bhh_f;
        bias2[rowg] = bi[r] + bh[r];
    }
}

// ---- embedding gather -> f16 X[b][t][128] ----
__global__ void k_gather(const int* __restrict__ ids, const float* __restrict__ emb,
                         f16* __restrict__ X) {
    int m = blockIdx.x * 2 + (threadIdx.x >> 7);
    int k = threadIdx.x & 127;
    int id = ids[m];
    X[(size_t)m * 128 + k] = (f16)emb[(size_t)id * 128 + k];
}

// ---- zero the sync flags ----
__global__ void k_zero(u32* __restrict__ flags) {
    flags[threadIdx.x] = 0u;
}

// ---- recurrence: 256 blocks = 2dir x 2half x 64b; 1024 thr; col-split rows ----
__global__ __launch_bounds__(1024, 1) void k_lstm(
        const f16* __restrict__ Whh_sw,  // [2][2][2][16][512][8]
        const f16* __restrict__ Wx_sw,   // [2][2][2][8][512][8]
        const float* __restrict__ bias2, // [2][1024]
        const f16* __restrict__ X,       // [64][1024][128]
        const float* __restrict__ fcw,   // [512]
        f16* __restrict__ Hx,            // [256 slots][2 parity][128]
        u32* __restrict__ flags,         // [256]
        float* __restrict__ Svp) {       // [4][64][1024]
    __shared__ __align__(16) f16 zxp[2][512][38];   // 77824 B x-projection tile (stride 38: bank-spread)
    __shared__ __align__(16) f16 sh_h[256];         // h (natural u order, both halves)
    __shared__ float zbuf[512];                     // gate activations (r-indexed)
    __shared__ float zpart[512];                    // q=1 partial z
    // total LDS 82432 B > 80 KiB -> exactly 1 block/CU

    const int blk  = blockIdx.x;
    const int dir  = blk >> 7;
    const int half = (blk >> 6) & 1;
    const int b    = blk & 63;
    const int tid  = threadIdx.x;
    const int q    = tid >> 9;       // wave-uniform column parity
    const int r    = tid & 511;      // row-in-block: g = r>>7, u = r&127
    const int g    = r >> 7;         // wave-uniform

    // ---- register weights: 16 chunks of 8 f16 = 64 VGPRs ----
    const half8_t* whp = (const half8_t*)Whh_sw + ((((size_t)dir * 2 + half) * 2 + q) * 16) * 512 + r;
    half8_t wh[16];
    #pragma unroll
    for (int c = 0; c < 16; ++c) wh[c] = whp[(size_t)c * 512];

    const float bias = bias2[dir * 1024 + g * 256 + half * 128 + (r & 127)];

    const f16* Xb = X + (size_t)b * S_ * 128;
    const int fidx_own = (dir * 64 + b) * 2 + half;
    const int fidx_par = fidx_own ^ 1;
    f16*       hx_own = Hx + (size_t)fidx_own * 2 * 128;
    const f16* hx_par = Hx + (size_t)fidx_par * 2 * 128;

    float cs0 = 0.f, cs1 = 0.f, fc0 = 0.f, fc1 = 0.f;
    if (tid < 64) {
        fc0 = fcw[dir * 256 + half * 128 + 2 * tid];
        fc1 = fcw[dir * 256 + half * 128 + 2 * tid + 1];
    }

    if (tid < 128) ((u32*)sh_h)[tid] = 0u;   // h_0 = 0, both halves
    __syncthreads();

    const int c_own = half * 8;              // own-half chunk indices
    const int c_par = 8 - half * 8;

    for (int s = 0; s < S_; ++s) {
        // ---- every 32 steps: x-projection phase (Wih streamed from L2) ----
        if ((s & 31) == 0) {
            const half8_t* wxp = (const half8_t*)Wx_sw +
                ((((size_t)dir * 2 + half) * 2 + q) * 8) * 512 + r;
            half8_t wx[8];
            #pragma unroll
            for (int c = 0; c < 8; ++c) wx[c] = wxp[(size_t)c * 512];
            for (int tp = 0; tp < 32; tp += 2) {
                int t0 = dir ? (S_ - 1 - (s + tp)) : (s + tp);
                int t1 = dir ? (t0 - 1) : (t0 + 1);
                const half8_t* x0 = (const half8_t*)&Xb[(size_t)t0 * 128] + q * 8;
                const half8_t* x1 = (const half8_t*)&Xb[(size_t)t1 * 128] + q * 8;
                float a0 = 0.f, a1 = 0.f;
                #pragma unroll
                for (int c = 0; c < 8; ++c) {
                    a0 = dot8(wx[c], x0[c], a0);
                    a1 = dot8(wx[c], x1[c], a1);
                }
                f16 p0 = (f16)a0, p1 = (f16)a1;
                u32 pk = (u32)__builtin_bit_cast(unsigned short, p0)
                       | ((u32)__builtin_bit_cast(unsigned short, p1) << 16);
                *(u32*)&zxp[q][r][tp] = pk;
            }
            __syncthreads();   // phase barrier: zxp tile ready
        }

        const int t = dir ? (S_ - 1 - s) : s;
        float acc = 0.f;

        // ---- phase 1: own-half h chunks ----
        #pragma unroll
        for (int c = 0; c < 8; ++c)
            acc = dot8(wh[c_own + c], *(const half8_t*)&sh_h[(2 * (c_own + c) + q) * 8], acc);

        // ---- wave 0: wait for partner h_s, stage into LDS ----
        if (s > 0 && tid < 64) {
            if (tid == 0) {
                while (__hip_atomic_load(&flags[fidx_par], __ATOMIC_ACQUIRE,
                                         __HIP_MEMORY_SCOPE_AGENT) < (u32)s)
                    __builtin_amdgcn_s_sleep(1);
            }
            if (tid < 16)
                *(half8_t*)&sh_h[(1 - half) * 128 + tid * 8] =
                    *(const half8_t*)&hx_par[(size_t)(s & 1) * 128 + tid * 8];
        }
        __syncthreads();   // B1: partner h staged

        // ---- phase 2: partner-half h chunks ----
        #pragma unroll
        for (int c = 0; c < 8; ++c)
            acc = dot8(wh[c_par + c], *(const half8_t*)&sh_h[(2 * (c_par + c) + q) * 8], acc);

        if (q == 1) zpart[r] = acc;
        __syncthreads();   // B2: partials ready

        if (q == 0) {
            float zx0 = (float)zxp[0][r][s & 31];
            float zx1 = (float)zxp[1][r][s & 31];
            float z = acc + zpart[r] + zx0 + zx1 + bias;
            zbuf[r] = (g == 2) ? fast_tanh(z) : fast_sig(z);
        }
        __syncthreads();   // B3: activations ready

        // ---- wave 0: combine (2 u's/lane), publish h, partial FC dot ----
        if (tid < 64) {
            const float2* zb2 = (const float2*)zbuf;
            float2 iv = zb2[tid];
            float2 fv = zb2[64 + tid];
            float2 gv = zb2[128 + tid];
            float2 ov = zb2[192 + tid];
            cs0 = fv.x * cs0 + iv.x * gv.x;
            cs1 = fv.y * cs1 + iv.y * gv.y;
            float h0 = ov.x * fast_tanh(cs0);
            float h1 = ov.y * fast_tanh(cs1);
            f16 h0h = (f16)h0, h1h = (f16)h1;
            u32 packed = (u32)__builtin_bit_cast(unsigned short, h0h)
                       | ((u32)__builtin_bit_cast(unsigned short, h1h) << 16);
            ((u32*)&sh_h[half * 128])[tid] = packed;
            ((u32*)&hx_own[(size_t)((s + 1) & 1) * 128])[tid] = packed;
            float ps = h0 * fc0 + h1 * fc1;
            #pragma unroll
            for (int off = 32; off > 0; off >>= 1) ps += __shfl_down(ps, off);
            if (tid == 0) {
                __hip_atomic_store(&flags[fidx_own], (u32)(s + 1), __ATOMIC_RELEASE,
                                   __HIP_MEMORY_SCOPE_AGENT);
                Svp[(((size_t)half * 2 + dir) * 64 + b) * S_ + t] = ps;
            }
        }
        __syncthreads();   // B4
    }
}

// ---- span pooling + FC ----
__global__ __launch_bounds__(256) void k_pool(const float* __restrict__ Svp, // [4][64][1024]
                                              const int* __restrict__ om,    // [64][1024][2]
                                              const int* __restrict__ pos,   // [64][32][2]
                                              const float* __restrict__ fcb,
                                              float* __restrict__ out) {     // [64][32]
    __shared__ float red[4][2];
    int bp = blockIdx.x;
    int b = bp >> 5, p = bp & 31;
    int ps = pos[(b * P_ + p) * 2];
    int pe = pos[(b * P_ + p) * 2 + 1];
    int tid = threadIdx.x;
    float sum = 0.f, cnt = 0.f;
    for (int j = tid; j < S_; j += 256) {
        int os = om[((size_t)b * S_ + j) * 2];
        int oe = om[((size_t)b * S_ + j) * 2 + 1];
        if (os >= ps && oe <= pe) {
            size_t base = (size_t)b * S_ + j;
            sum += Svp[0 * 65536 + base] + Svp[1 * 65536 + base]
                 + Svp[2 * 65536 + base] + Svp[3 * 65536 + base];
            cnt += 1.f;
        }
    }
    #pragma unroll
    for (int off = 32; off > 0; off >>= 1) {
        sum += __shfl_down(sum, off);
        cnt += __shfl_down(cnt, off);
    }
    if ((tid & 63) == 0) { red[tid >> 6][0] = sum; red[tid >> 6][1] = cnt; }
    __syncthreads();
    if (tid == 0) {
        sum = red[0][0] + red[1][0] + red[2][0] + red[3][0];
        cnt = red[0][1] + red[1][1] + red[2][1] + red[3][1];
        bool valid = (cnt > 0.f) && !(ps == 0 && pe == 0);
        float v = valid ? (sum / fmaxf(cnt, 1.f)) : 0.f;
        out[b * P_ + p] = v + fcb[0];
    }
}

extern "C" void kernel_launch(void* const* d_in, const int* in_sizes, int n_in,
                              void* d_out, int out_size, void* d_ws, size_t ws_size,
                              hipStream_t stream) {
    const float* emb   = (const float*)d_in[0];
    const float* wih_f = (const float*)d_in[1];
    const float* whh_f = (const float*)d_in[2];
    const float* bih_f = (const float*)d_in[3];
    const float* bhh_f = (const float*)d_in[4];
    const float* wih_b = (const float*)d_in[5];
    const float* whh_b = (const float*)d_in[6];
    const float* bih_b = (const float*)d_in[7];
    const float* bhh_b = (const float*)d_in[8];
    const float* fc_w  = (const float*)d_in[9];
    const float* fc_b  = (const float*)d_in[10];
    const int* ids     = (const int*)d_in[11];
    const int* om      = (const int*)d_in[13];
    const int* pos     = (const int*)d_in[14];

    char* ws = (char*)d_ws;
    f16*   X      = (f16*)(ws + 0);            // 16,777,216
    f16*   WhhSw  = (f16*)(ws + 16777216);     //  2,097,152
    f16*   WxSw   = (f16*)(ws + 18874368);     //  1,048,576
    float* bias2  = (float*)(ws + 19922944);   //      8,192
    f16*   Hx     = (f16*)(ws + 19931136);     //    131,072
    u32*   flags  = (u32*)(ws + 20062208);     //      1,024
    float* Svp    = (float*)(ws + 20063232);   //  1,048,576
    float* out    = (float*)d_out;             // total ws ≈ 21.1 MB

    k_prep_w<<<2048, 384, 0, stream>>>(wih_f, whh_f, bih_f, bhh_f,
                                       wih_b, whh_b, bih_b, bhh_b, WhhSw, WxSw, bias2);
    k_gather<<<32768, 256, 0, stream>>>(ids, emb, X);
    k_zero<<<1, 256, 0, stream>>>(flags);
    k_lstm<<<256, 1024, 0, stream>>>(WhhSw, WxSw, bias2, X, fc_w, Hx, flags, Svp);
    k_pool<<<2048, 256, 0, stream>>>(Svp, om, pos, fc_b, out);
}

// Round 7
// 16876.871 us; speedup vs baseline: 1.0364x; 1.0364x over previous
//
#include <hip/hip_runtime.h>

#define S_  1024
#define B_  64
#define P_  32

typedef _Float16 f16;
typedef unsigned int u32;
typedef _Float16 half2_t __attribute__((ext_vector_type(2)));
typedef _Float16 half8_t __attribute__((ext_vector_type(8)));

__device__ __forceinline__ float dot8(half8_t w, half8_t h, float acc) {
#if __has_builtin(__builtin_amdgcn_fdot2)
    acc = __builtin_amdgcn_fdot2((half2_t){w[0], w[1]}, (half2_t){h[0], h[1]}, acc, false);
    acc = __builtin_amdgcn_fdot2((half2_t){w[2], w[3]}, (half2_t){h[2], h[3]}, acc, false);
    acc = __builtin_amdgcn_fdot2((half2_t){w[4], w[5]}, (half2_t){h[4], h[5]}, acc, false);
    acc = __builtin_amdgcn_fdot2((half2_t){w[6], w[7]}, (half2_t){h[6], h[7]}, acc, false);
#else
    #pragma unroll
    for (int j = 0; j < 8; ++j) acc += (float)w[j] * (float)h[j];
#endif
    return acc;
}

__device__ __forceinline__ float fast_sig(float x)  { return 1.f / (1.f + __expf(-x)); }
__device__ __forceinline__ float fast_tanh(float x) { return 1.f - 2.f / (1.f + __expf(2.f * x)); }

// ---- prep: swizzle weights for k_lstm ----
// Row r (within dir): g=r>>8, half=(r>>7)&1, u=r&127, rloc=g*128+u (0..511).
// Whh_sw[dir][half][c 0..31][rloc 512][8]   (c = h-column chunk, global u order)
// Wx_sw [dir][half][c 0..15][rloc 512][8]
__global__ void k_prep_w(const float* __restrict__ wih_f, const float* __restrict__ whh_f,
                         const float* __restrict__ bih_f, const float* __restrict__ bhh_f,
                         const float* __restrict__ wih_b, const float* __restrict__ whh_b,
                         const float* __restrict__ bih_b, const float* __restrict__ bhh_b,
                         f16* __restrict__ Whh_sw, f16* __restrict__ Wx_sw,
                         float* __restrict__ bias2) {
    int rowg = blockIdx.x;          // 0..2047
    int dir = rowg >> 10;
    int r = rowg & 1023;
    int col = threadIdx.x;          // 0..383
    int g = r >> 8, half = (r >> 7) & 1, u = r & 127;
    int rloc = g * 128 + u;
    const float* wih = dir ? wih_b : wih_f;
    const float* whh = dir ? whh_b : whh_f;
    if (col < 128) {
        int c = col >> 3, j = col & 7;
        Wx_sw[((((size_t)(dir * 2 + half)) * 16 + c) * 512 + rloc) * 8 + j] =
            (f16)wih[r * 128 + col];
    } else {
        int v = col - 128;              // 0..255 global h-column
        int c = v >> 3, j = v & 7;
        Whh_sw[((((size_t)(dir * 2 + half)) * 32 + c) * 512 + rloc) * 8 + j] =
            (f16)whh[r * 256 + v];
    }
    if (col == 0) {
        const float* bi = dir ? bih_b : bih_f;
        const float* bh = dir ? bhh_b : bhh_f;
        bias2[rowg] = bi[r] + bh[r];
    }
}

// ---- embedding gather -> f16 X[b][t][128] ----
__global__ void k_gather(const int* __restrict__ ids, const float* __restrict__ emb,
                         f16* __restrict__ X) {
    int m = blockIdx.x * 2 + (threadIdx.x >> 7);
    int k = threadIdx.x & 127;
    int id = ids[m];
    X[(size_t)m * 128 + k] = (f16)emb[(size_t)id * 128 + k];
}

// ---- zero the sync flags ----
__global__ void k_zero(u32* __restrict__ flags) {
    flags[threadIdx.x] = 0u;
}

// ---- recurrence: 256 blocks = 2dir x 2half x 64b; 512 thr; 1 row/thread ----
// 32 weight chunks (=128 VGPRs) pinned in registers via empty asm.
__global__ __launch_bounds__(512, 2) void k_lstm(
        const f16* __restrict__ Whh_sw,  // [2][2][32][512][8]
        const f16* __restrict__ Wx_sw,   // [2][2][16][512][8]
        const float* __restrict__ bias2, // [2][1024]
        const f16* __restrict__ X,       // [64][1024][128]
        const float* __restrict__ fcw,   // [512]
        f16* __restrict__ Hx,            // [256 slots][2 parity][128]
        u32* __restrict__ flags,         // [256]
        float* __restrict__ Svp) {       // [4][64][1024]
    __shared__ __align__(16) f16 zxp[512][38];   // 38,912 B x-proj tile (stride 38: bank-spread)
    __shared__ __align__(16) f16 sh_h[256];      // h, global u order (half0 | half1)
    __shared__ float zbuf[512];                  // gate activations (rloc-indexed)

    const int blk  = blockIdx.x;
    const int dir  = blk >> 7;
    const int half = (blk >> 6) & 1;
    const int b    = blk & 63;
    const int tid  = threadIdx.x;    // == rloc; g = tid>>7 (wave-uniform)
    const int g    = tid >> 7;

    // ---- register weights: 32 chunks of 8 f16 = 128 VGPRs, pinned ----
    const half8_t* whp = (const half8_t*)Whh_sw + ((size_t)(dir * 2 + half) * 32) * 512 + tid;
    half8_t wh[32];
    #pragma unroll
    for (int c = 0; c < 32; ++c) wh[c] = whp[(size_t)c * 512];
    // pin: make values opaque so the compiler cannot re-sink the loads into the loop
    asm volatile("" : "+v"(wh[0]), "+v"(wh[1]), "+v"(wh[2]), "+v"(wh[3]),
                      "+v"(wh[4]), "+v"(wh[5]), "+v"(wh[6]), "+v"(wh[7]));
    asm volatile("" : "+v"(wh[8]), "+v"(wh[9]), "+v"(wh[10]), "+v"(wh[11]),
                      "+v"(wh[12]), "+v"(wh[13]), "+v"(wh[14]), "+v"(wh[15]));
    asm volatile("" : "+v"(wh[16]), "+v"(wh[17]), "+v"(wh[18]), "+v"(wh[19]),
                      "+v"(wh[20]), "+v"(wh[21]), "+v"(wh[22]), "+v"(wh[23]));
    asm volatile("" : "+v"(wh[24]), "+v"(wh[25]), "+v"(wh[26]), "+v"(wh[27]),
                      "+v"(wh[28]), "+v"(wh[29]), "+v"(wh[30]), "+v"(wh[31]));

    const float bias = bias2[dir * 1024 + g * 256 + half * 128 + (tid & 127)];

    const f16* Xb = X + (size_t)b * S_ * 128;
    const int fidx_own = (dir * 64 + b) * 2 + half;
    const int fidx_par = fidx_own ^ 1;
    f16*       hx_own = Hx + (size_t)fidx_own * 2 * 128;
    const f16* hx_par = Hx + (size_t)fidx_par * 2 * 128;

    float cs0 = 0.f, cs1 = 0.f, fc0 = 0.f, fc1 = 0.f;
    if (tid < 64) {
        fc0 = fcw[dir * 256 + half * 128 + 2 * tid];
        fc1 = fcw[dir * 256 + half * 128 + 2 * tid + 1];
    }

    if (tid < 128) ((u32*)sh_h)[tid] = 0u;   // h_0 = 0, both halves
    __syncthreads();

    const half8_t* shh = (const half8_t*)sh_h;   // 32 chunks: 0..15 half0, 16..31 half1
    const int c_own = half * 16;
    const int c_par = 16 - half * 16;

    for (int s = 0; s < S_; ++s) {
        // ---- every 32 steps: x-projection tile (Wih streamed, amortized) ----
        if ((s & 31) == 0) {
            const half8_t* wxp = (const half8_t*)Wx_sw +
                ((size_t)(dir * 2 + half) * 16) * 512 + tid;
            half8_t wx[16];
            #pragma unroll
            for (int c = 0; c < 16; ++c) wx[c] = wxp[(size_t)c * 512];
            for (int tp = 0; tp < 32; tp += 2) {
                int t0 = dir ? (S_ - 1 - (s + tp)) : (s + tp);
                int t1 = dir ? (t0 - 1) : (t0 + 1);
                const half8_t* x0 = (const half8_t*)&Xb[(size_t)t0 * 128];
                const half8_t* x1 = (const half8_t*)&Xb[(size_t)t1 * 128];
                float a0 = 0.f, a1 = 0.f;
                #pragma unroll
                for (int c = 0; c < 16; ++c) {
                    a0 = dot8(wx[c], x0[c], a0);
                    a1 = dot8(wx[c], x1[c], a1);
                }
                f16 p0 = (f16)a0, p1 = (f16)a1;
                u32 pk = (u32)__builtin_bit_cast(unsigned short, p0)
                       | ((u32)__builtin_bit_cast(unsigned short, p1) << 16);
                *(u32*)&zxp[tid][tp] = pk;
            }
            __syncthreads();   // zxp tile ready
        }

        const int t = dir ? (S_ - 1 - s) : s;
        float acc = 0.f;

        // ---- phase 1: own-half h chunks (ready from prev step) ----
        #pragma unroll
        for (int c = 0; c < 16; ++c)
            acc = dot8(wh[c_own + c], shh[c_own + c], acc);

        // ---- wave 0: wait for partner h_s, stage into LDS ----
        if (s > 0 && tid < 64) {
            if (tid == 0) {
                while (__hip_atomic_load(&flags[fidx_par], __ATOMIC_ACQUIRE,
                                         __HIP_MEMORY_SCOPE_AGENT) < (u32)s)
                    __builtin_amdgcn_s_sleep(1);
            }
            if (tid < 16)
                *(half8_t*)&sh_h[(1 - half) * 128 + tid * 8] =
                    *(const half8_t*)&hx_par[(size_t)(s & 1) * 128 + tid * 8];
        }
        __syncthreads();   // B1: partner h staged

        // ---- phase 2: partner-half h chunks ----
        #pragma unroll
        for (int c = 0; c < 16; ++c)
            acc = dot8(wh[c_par + c], shh[c_par + c], acc);

        float zx = (float)zxp[tid][s & 31];
        float z = acc + zx + bias;
        zbuf[tid] = (g == 2) ? fast_tanh(z) : fast_sig(z);
        __syncthreads();   // B2: activations ready

        // ---- wave 0: combine (2 u's/lane), publish h, partial FC dot ----
        if (tid < 64) {
            const float2* zb2 = (const float2*)zbuf;
            float2 iv = zb2[tid];
            float2 fv = zb2[64 + tid];
            float2 gv = zb2[128 + tid];
            float2 ov = zb2[192 + tid];
            cs0 = fv.x * cs0 + iv.x * gv.x;
            cs1 = fv.y * cs1 + iv.y * gv.y;
            float h0 = ov.x * fast_tanh(cs0);
            float h1 = ov.y * fast_tanh(cs1);
            f16 h0h = (f16)h0, h1h = (f16)h1;
            u32 packed = (u32)__builtin_bit_cast(unsigned short, h0h)
                       | ((u32)__builtin_bit_cast(unsigned short, h1h) << 16);
            ((u32*)&sh_h[half * 128])[tid] = packed;
            ((u32*)&hx_own[(size_t)((s + 1) & 1) * 128])[tid] = packed;
            float ps = h0 * fc0 + h1 * fc1;
            #pragma unroll
            for (int off = 32; off > 0; off >>= 1) ps += __shfl_down(ps, off);
            if (tid == 0) {
                __hip_atomic_store(&flags[fidx_own], (u32)(s + 1), __ATOMIC_RELEASE,
                                   __HIP_MEMORY_SCOPE_AGENT);
                Svp[(((size_t)half * 2 + dir) * 64 + b) * S_ + t] = ps;
            }
        }
        __syncthreads();   // B3: h_{s+1} staged; zbuf/zxp consumable
    }
}

// ---- span pooling + FC ----
__global__ __launch_bounds__(256) void k_pool(const float* __restrict__ Svp, // [4][64][1024]
                                              const int* __restrict__ om,    // [64][1024][2]
                                              const int* __restrict__ pos,   // [64][32][2]
                                              const float* __restrict__ fcb,
                                              float* __restrict__ out) {     // [64][32]
    __shared__ float red[4][2];
    int bp = blockIdx.x;
    int b = bp >> 5, p = bp & 31;
    int ps = pos[(b * P_ + p) * 2];
    int pe = pos[(b * P_ + p) * 2 + 1];
    int tid = threadIdx.x;
    float sum = 0.f, cnt = 0.f;
    for (int j = tid; j < S_; j += 256) {
        int os = om[((size_t)b * S_ + j) * 2];
        int oe = om[((size_t)b * S_ + j) * 2 + 1];
        if (os >= ps && oe <= pe) {
            size_t base = (size_t)b * S_ + j;
            sum += Svp[0 * 65536 + base] + Svp[1 * 65536 + base]
                 + Svp[2 * 65536 + base] + Svp[3 * 65536 + base];
            cnt += 1.f;
        }
    }
    #pragma unroll
    for (int off = 32; off > 0; off >>= 1) {
        sum += __shfl_down(sum, off);
        cnt += __shfl_down(cnt, off);
    }
    if ((tid & 63) == 0) { red[tid >> 6][0] = sum; red[tid >> 6][1] = cnt; }
    __syncthreads();
    if (tid == 0) {
        sum = red[0][0] + red[1][0] + red[2][0] + red[3][0];
        cnt = red[0][1] + red[1][1] + red[2][1] + red[3][1];
        bool valid = (cnt > 0.f) && !(ps == 0 && pe == 0);
        float v = valid ? (sum / fmaxf(cnt, 1.f)) : 0.f;
        out[b * P_ + p] = v + fcb[0];
    }
}

extern "C" void kernel_launch(void* const* d_in, const int* in_sizes, int n_in,
                              void* d_out, int out_size, void* d_ws, size_t ws_size,
                              hipStream_t stream) {
    const float* emb   = (const float*)d_in[0];
    const float* wih_f = (const float*)d_in[1];
    const float* whh_f = (const float*)d_in[2];
    const float* bih_f = (const float*)d_in[3];
    const float* bhh_f = (const float*)d_in[4];
    const float* wih_b = (const float*)d_in[5];
    const float* whh_b = (const float*)d_in[6];
    const float* bih_b = (const float*)d_in[7];
    const float* bhh_b = (const float*)d_in[8];
    const float* fc_w  = (const float*)d_in[9];
    const float* fc_b  = (const float*)d_in[10];
    const int* ids     = (const int*)d_in[11];
    const int* om      = (const int*)d_in[13];
    const int* pos     = (const int*)d_in[14];

    char* ws = (char*)d_ws;
    f16*   X      = (f16*)(ws + 0);            // 16,777,216
    f16*   WhhSw  = (f16*)(ws + 16777216);     //  1,048,576
    f16*   WxSw   = (f16*)(ws + 17825792);     //    524,288
    float* bias2  = (float*)(ws + 18350080);   //      8,192
    f16*   Hx     = (f16*)(ws + 18358272);     //    131,072
    u32*   flags  = (u32*)(ws + 18489344);     //      1,024
    float* Svp    = (float*)(ws + 18490368);   //  1,048,576
    float* out    = (float*)d_out;             // total ws ≈ 19.5 MB

    k_prep_w<<<2048, 384, 0, stream>>>(wih_f, whh_f, bih_f, bhh_f,
                                       wih_b, whh_b, bih_b, bhh_b, WhhSw, WxSw, bias2);
    k_gather<<<32768, 256, 0, stream>>>(ids, emb, X);
    k_zero<<<1, 256, 0, stream>>>(flags);
    k_lstm<<<256, 512, 0, stream>>>(WhhSw, WxSw, bias2, X, fc_w, Hx, flags, Svp);
    k_pool<<<2048, 256, 0, stream>>>(Svp, om, pos, fc_b, out);
}